// Round 8
// baseline (278.079 us; speedup 1.0000x reference)
//
#include <hip/hip_runtime.h>

typedef __bf16 bf16;
typedef __bf16 bf16x2 __attribute__((ext_vector_type(2)));
typedef __bf16 bf16x4 __attribute__((ext_vector_type(4)));
typedef __bf16 bf16x8 __attribute__((ext_vector_type(8)));
typedef float  f32x4  __attribute__((ext_vector_type(4)));
typedef float  f32x16 __attribute__((ext_vector_type(16)));
typedef unsigned int u32;
typedef unsigned int u32x2 __attribute__((ext_vector_type(2)));
typedef unsigned int u32x4 __attribute__((ext_vector_type(4)));

#define LOG2E 1.44269504088896340736f
#define EXP_SC (0.125f * LOG2E)   // folded into Q at the QKV-GEMM epilogue

#if __has_builtin(__builtin_amdgcn_exp2f)
#define EXP2F(x) __builtin_amdgcn_exp2f(x)
#else
#define EXP2F(x) __builtin_exp2f(x)
#endif

// fast f32 -> bf16 (round-half-up) packed pair via v_perm_b32
__device__ __forceinline__ u32 pk_bf16(float lo, float hi) {
  u32 a = __float_as_uint(lo) + 0x8000u;
  u32 b = __float_as_uint(hi) + 0x8000u;
  return __builtin_amdgcn_perm(b, a, 0x07060302);  // [bf16(lo) | bf16(hi)<<16]
}
#if __has_builtin(__builtin_amdgcn_cvt_pk_bf16_f32)
__device__ __forceinline__ u32 cvtpk(float lo, float hi) {
  bf16x2 t = __builtin_amdgcn_cvt_pk_bf16_f32(lo, hi);
  return __builtin_bit_cast(u32, t);
}
#else
__device__ __forceinline__ u32 cvtpk(float lo, float hi) { return pk_bf16(lo, hi); }
#endif
__device__ __forceinline__ unsigned short bf16r(float x) {
  return (unsigned short)((__float_as_uint(x) + 0x8000u) >> 16);
}

__device__ __forceinline__ f32x16 zero16() {
  f32x16 a;
#pragma unroll
  for (int i = 0; i < 16; i++) a[i] = 0.f;
  return a;
}

// async global->LDS, 16B per lane. LDS dest = wave-uniform base + lane*16.
__device__ __forceinline__ void async_ld16(void* lds, const void* g) {
  __builtin_amdgcn_global_load_lds(
      (const __attribute__((address_space(1))) void*)(g),
      (__attribute__((address_space(3))) void*)(lds),
      16, 0, 0);
}

// ---------------------------------------------------------------------------
// Fused prep: one launch, three block ranges (phases overlap across CUs).
//   [0, 8192)      : x fp32 -> xb bf16 (4 elems/thread)
//   [8192, 8448)   : WT_perm[n'][k] = bf16(W_qkv[k][orig_n(n')]),
//                    n' = wch*1024+h*64+dl where the GEMM-local d index dl
//                    maps to true d = (dl&15)*4 + (dl>>4)  [epilogue packing]
//   [8448, 8576)   : WoT[n][k] = bf16(W_o[k][n])
// ---------------------------------------------------------------------------
__global__ void prep_all(const float* __restrict__ x,    bf16* __restrict__ xb,
                         const float* __restrict__ Wqkv, bf16* __restrict__ wqkvT,
                         const float* __restrict__ Wo,   bf16* __restrict__ woT) {
  __shared__ float s[12288];                // 48 KB
  const int bid = blockIdx.x;
  const int tid = threadIdx.x;
  if (bid < 8192) {
    int i = bid * 256 + tid;
    float4 v = ((const float4*)x)[i];
    u32x2 o = { pk_bf16(v.x, v.y), pk_bf16(v.z, v.w) };
    *(u32x2*)(xb + (size_t)i * 4) = o;
  } else if (bid < 8448) {
    const int k0 = (bid - 8192) * 4;
    for (int i = tid; i < 3072; i += 256) {       // 4 rows * 768 float4
      int r = i / 768, c = (i - r * 768) * 4;
      *(float4*)(s + r * 3072 + c) = *(const float4*)(Wqkv + (size_t)(k0 + r) * 3072 + c);
    }
    __syncthreads();
    for (int n = tid; n < 3072; n += 256) {
      int dl = n & 63, h = (n >> 6) & 15, wch = n >> 10;
      int d = ((dl & 15) << 2) | (dl >> 4);       // column->d permutation
      int on = d * 48 + wch * 16 + h;
      u32x2 v = { pk_bf16(s[0 * 3072 + on], s[1 * 3072 + on]),
                  pk_bf16(s[2 * 3072 + on], s[3 * 3072 + on]) };
      *(u32x2*)(wqkvT + (size_t)n * 1024 + k0) = v;
    }
  } else {
    const int k0 = (bid - 8448) * 8;
    for (int i = tid; i < 2048; i += 256) {       // 8 rows * 256 float4
      int r = i >> 8, c = (i & 255) * 4;
      *(float4*)(s + r * 1024 + c) = *(const float4*)(Wo + (size_t)(k0 + r) * 1024 + c);
    }
    __syncthreads();
    for (int n = tid; n < 1024; n += 256) {
      u32x4 v = { pk_bf16(s[0 * 1024 + n], s[1 * 1024 + n]),
                  pk_bf16(s[2 * 1024 + n], s[3 * 1024 + n]),
                  pk_bf16(s[4 * 1024 + n], s[5 * 1024 + n]),
                  pk_bf16(s[6 * 1024 + n], s[7 * 1024 + n]) };
      *(u32x4*)(woT + (size_t)n * 1024 + k0) = v;
    }
  }
}

// ---------------------------------------------------------------------------
// GEMM: C = A[M][1024] * BT[N][1024]^T, 128x128 tile, BK=64, 4 waves.
// Single-buffer, 2 barriers per K-step (best measured GEMM structure).
// __launch_bounds__(256, 4): forces VGPR <= 128 -> 4 blocks/CU (16 waves).
// At (256,2) the compiler allocated freely (cap 256) -> ~3 blocks/CU; this
// latency-exposed structure (full vmcnt(0) drain at the post-stage barrier
// every K-step) needs wave count to cover the stall. Live set ~120 regs
// (acc 64 + af/bfr 32 + addressing) -- fits under 128.
// MODE 0: fp32 C. MODE 1: packed bf16 stores; weight-column permutation
// (true d = (col&15)*4 + ((col>>4)&3)) makes each lane's 4 ns-fragments
// consecutive d -> Q/K u32x2 at [bh][t][d0=l15*4]; V packs along r
// (4 consecutive t) -> u32x2 at VT[bh][d][t]. Q pre-scaled.
// ---------------------------------------------------------------------------
template <int MODE>
__launch_bounds__(256, 4)
__global__ void gemm_bt(const bf16* __restrict__ A, const bf16* __restrict__ BT,
                        float* __restrict__ C, int N,
                        bf16* __restrict__ Qb, bf16* __restrict__ Kb, bf16* __restrict__ Vb) {
  constexpr int K = 1024;
  __shared__ bf16 sA[128 * 64];             // 16 KB
  __shared__ bf16 sB[128 * 64];             // 16 KB
  const int m0 = blockIdx.x * 128;
  const int n0 = blockIdx.y * 128;
  const int tid = threadIdx.x;
  const int lane = tid & 63;
  const int w = tid >> 6;
  const int wm = (w >> 1) * 64, wn = (w & 1) * 64;
  const int l15 = lane & 15, quad = lane >> 4;

  f32x4 acc[4][4];
  for (int i = 0; i < 4; i++)
    for (int j = 0; j < 4; j++) acc[i][j] = f32x4{0.f, 0.f, 0.f, 0.f};

  const int rT = tid >> 3;
  const int jT = (tid & 7) ^ (rT & 7);
  const bf16* gA = A  + (size_t)(m0 + rT) * K + jT * 8;
  const bf16* gB = BT + (size_t)(n0 + rT) * K + jT * 8;

  for (int k0 = 0; k0 < K; k0 += 64) {
    __syncthreads();
    for (int i = 0; i < 4; i++) {
      async_ld16((void*)(sA + (i * 256 + w * 64) * 8), gA + (size_t)i * 32 * K);
      async_ld16((void*)(sB + (i * 256 + w * 64) * 8), gB + (size_t)i * 32 * K);
    }
    gA += 64; gB += 64;
    __syncthreads();

    for (int kk = 0; kk < 2; kk++) {
      bf16x8 af[4], bfr[4];
      for (int ms = 0; ms < 4; ms++) {
        int r = wm + ms * 16 + l15;
        af[ms] = *(const bf16x8*)(sA + r * 64 + (((kk * 4 + quad) ^ (r & 7)) * 8));
      }
      for (int ns = 0; ns < 4; ns++) {
        int r = wn + ns * 16 + l15;
        bfr[ns] = *(const bf16x8*)(sB + r * 64 + (((kk * 4 + quad) ^ (r & 7)) * 8));
      }
      for (int ms = 0; ms < 4; ms++)
        for (int ns = 0; ns < 4; ns++)
          acc[ms][ns] = __builtin_amdgcn_mfma_f32_16x16x32_bf16(af[ms], bfr[ns], acc[ms][ns], 0, 0, 0);
    }
  }

  if (MODE == 0) {
    for (int ms = 0; ms < 4; ms++)
      for (int ns = 0; ns < 4; ns++)
        for (int r = 0; r < 4; r++) {
          int row = m0 + wm + ms * 16 + quad * 4 + r;
          int col = n0 + wn + ns * 16 + l15;
          C[(size_t)row * N + col] = acc[ms][ns][r];
        }
  } else {
    const int col0 = n0 + wn;                 // 64-aligned: one head per wave
    const int wch = col0 >> 10;               // uniform per block
    const int h = (col0 >> 6) & 15;           // uniform per wave
    if (wch != 2) {
      bf16* dst = (wch == 0) ? Qb : Kb;
      const float sc = (wch == 0) ? EXP_SC : 1.0f;
      for (int ms = 0; ms < 4; ms++)
        for (int r = 0; r < 4; r++) {
          int row = m0 + wm + ms * 16 + quad * 4 + r;
          int b = row >> 11, t = row & 2047;
          u32x2 v = { cvtpk(acc[ms][0][r] * sc, acc[ms][1][r] * sc),
                      cvtpk(acc[ms][2][r] * sc, acc[ms][3][r] * sc) };
          *(u32x2*)((unsigned short*)dst +
                    (((size_t)(b * 16 + h)) * 2048 + t) * 64 + l15 * 4) = v;
        }
    } else {
      for (int ms = 0; ms < 4; ms++)
        for (int ns = 0; ns < 4; ns++) {
          int row = m0 + wm + ms * 16 + quad * 4;   // rows row..row+3 = consecutive t
          int b = row >> 11, t = row & 2047;
          int d = l15 * 4 + ns;                      // permuted column -> true d
          u32x2 v = { cvtpk(acc[ms][ns][0], acc[ms][ns][1]),
                      cvtpk(acc[ms][ns][2], acc[ms][ns][3]) };
          *(u32x2*)((unsigned short*)Vb +
                    (((size_t)(b * 16 + h)) * 64 + d) * 2048 + t) = v;
        }
    }
  }
}

// ---------------------------------------------------------------------------
// Flash attention, swapped-operand 32x32 MFMA, P in registers, 2 q-blocks
// per wave, ONE barrier per tile (R7, best measured: 87.0 us; ~790 TF =
// this schedule family's ceiling per R1/R4/R7 A/B). UNCHANGED this round.
// ---------------------------------------------------------------------------
__launch_bounds__(256, 2)
__global__ void attn_fwd(const bf16* __restrict__ Q, const bf16* __restrict__ K,
                         const bf16* __restrict__ VT, bf16* __restrict__ O) {
  __shared__ bf16 sK[2][64 * 64];           // 16 KB  [key][d]
  __shared__ bf16 sV[2][64 * 64];           // 16 KB  [d][key]
  const int bh = blockIdx.x;
  const int q0 = blockIdx.y * 256;
  const int tid = threadIdx.x;
  const int lane = tid & 63, w = tid >> 6;
  const int l31 = lane & 31, hi = lane >> 5;

  // Q B-fragments for both q-blocks (col = q = l31, k = kq*16 + hi*8 + j)
  bf16x8 qf[2][4];
#pragma unroll
  for (int qb = 0; qb < 2; qb++) {
    const bf16* qp = Q + ((size_t)bh * 2048 + q0 + qb * 128 + w * 32 + l31) * 64 + hi * 8;
#pragma unroll
    for (int kq = 0; kq < 4; kq++) qf[qb][kq] = *(const bf16x8*)(qp + kq * 16);
  }

  f32x16 oacc[2][2];                        // [qb][ds]
  oacc[0][0] = zero16(); oacc[0][1] = zero16();
  oacc[1][0] = zero16(); oacc[1][1] = zero16();
  float rs[2] = {0.f, 0.f};

  // staging geometry: 512 16B chunks per 8KB tile.
  const int cA = w * 128 + lane;
  const int rA = cA >> 3, jA = (cA & 7) ^ (rA & 7);
  const bf16* gK = K  + ((size_t)bh * 2048 + rA) * 64 + jA * 8;   // +512: row+8
  const bf16* gV = VT + ((size_t)bh * 64 + rA) * 2048 + jA * 8;   // +16384: row+8

  // fragment offsets: row = sub*32 + l31, chunk = st*2 + hi,
  // addr = r*64 + ((chunk ^ (r&7)) * 8). Serves K (sub=ks) and V (sub=ds).
  int fo[2][4];
#pragma unroll
  for (int sub = 0; sub < 2; sub++)
#pragma unroll
    for (int st = 0; st < 4; st++) {
      int r = sub * 32 + l31;
      fo[sub][st] = r * 64 + (((st * 2 + hi) ^ (r & 7)) * 8);
    }

  auto stage = [&](bf16* kb, bf16* vb) {
    async_ld16((void*)(kb + w * 1024),        gK);
    async_ld16((void*)(kb + w * 1024 + 512),  gK + 512);
    async_ld16((void*)(vb + w * 1024),        gV);
    async_ld16((void*)(vb + w * 1024 + 512),  gV + 16384);
    gK += 4096; gV += 64;
  };

  auto expF = [&](f32x16 (&S)[2], bf16x8 (&F)[4], float& rsv) {
#pragma unroll
    for (int ks = 0; ks < 2; ks++) {
      float p[16];
#pragma unroll
      for (int r = 0; r < 16; r++) p[r] = EXP2F(S[ks][r]);
      rsv += (((p[0] + p[1]) + (p[2] + p[3])) + ((p[4] + p[5]) + (p[6] + p[7])))
           + (((p[8] + p[9]) + (p[10] + p[11])) + ((p[12] + p[13]) + (p[14] + p[15])));
      u32 c0 = cvtpk(p[0],  p[1]),  c1 = cvtpk(p[2],  p[3]);
      u32 c2 = cvtpk(p[4],  p[5]),  c3 = cvtpk(p[6],  p[7]);
      u32 c4 = cvtpk(p[8],  p[9]),  c5 = cvtpk(p[10], p[11]);
      u32 c6 = cvtpk(p[12], p[13]), c7 = cvtpk(p[14], p[15]);
      asm("v_permlane32_swap_b32 %0, %1" : "+v"(c0), "+v"(c2));
      asm("v_permlane32_swap_b32 %0, %1" : "+v"(c1), "+v"(c3));
      asm("v_permlane32_swap_b32 %0, %1" : "+v"(c4), "+v"(c6));
      asm("v_permlane32_swap_b32 %0, %1" : "+v"(c5), "+v"(c7));
      u32x4 f0 = { c0, c1, c2, c3 };
      u32x4 f1 = { c4, c5, c6, c7 };
      F[ks * 2 + 0] = __builtin_bit_cast(bf16x8, f0);
      F[ks * 2 + 1] = __builtin_bit_cast(bf16x8, f1);
    }
  };

  // prologue: stage tile 0 -> sK[0], sV[0]
  stage(sK[0], sV[0]);

  for (int t = 0; t < 32; ++t) {
    __syncthreads();                        // tile t landed; iter t-1 reads done
    const bf16* kb = sK[t & 1];
    const bf16* vb = sV[t & 1];
    // issue kf ds_reads first (LDS pipe starts), then vmem stage issue
    bf16x8 kf[2][4];
#pragma unroll
    for (int ks = 0; ks < 2; ks++)
#pragma unroll
      for (int kq = 0; kq < 4; kq++)
        kf[ks][kq] = *(const bf16x8*)(kb + fo[ks][kq]);
    if (t < 31) stage(sK[(t + 1) & 1], sV[(t + 1) & 1]);

    // QK for both q-blocks (16 MFMA, 4 independent 4-chains)
    f32x16 S0[2], S1[2];
    __builtin_amdgcn_s_setprio(1);
#pragma unroll
    for (int ks = 0; ks < 2; ks++) {
      f32x16 a = zero16();
      a = __builtin_amdgcn_mfma_f32_32x32x16_bf16(kf[ks][0], qf[0][0], a, 0, 0, 0);
      a = __builtin_amdgcn_mfma_f32_32x32x16_bf16(kf[ks][1], qf[0][1], a, 0, 0, 0);
      a = __builtin_amdgcn_mfma_f32_32x32x16_bf16(kf[ks][2], qf[0][2], a, 0, 0, 0);
      a = __builtin_amdgcn_mfma_f32_32x32x16_bf16(kf[ks][3], qf[0][3], a, 0, 0, 0);
      S0[ks] = a;
    }
#pragma unroll
    for (int ks = 0; ks < 2; ks++) {
      f32x16 a = zero16();
      a = __builtin_amdgcn_mfma_f32_32x32x16_bf16(kf[ks][0], qf[1][0], a, 0, 0, 0);
      a = __builtin_amdgcn_mfma_f32_32x32x16_bf16(kf[ks][1], qf[1][1], a, 0, 0, 0);
      a = __builtin_amdgcn_mfma_f32_32x32x16_bf16(kf[ks][2], qf[1][2], a, 0, 0, 0);
      a = __builtin_amdgcn_mfma_f32_32x32x16_bf16(kf[ks][3], qf[1][3], a, 0, 0, 0);
      S1[ks] = a;
    }
    __builtin_amdgcn_s_setprio(0);

    // exp0 on VALU while QK1 drains the MFMA pipe
    bf16x8 F[4];
    expF(S0, F, rs[0]);

    bf16x8 vf[2][4];
#pragma unroll
    for (int ds = 0; ds < 2; ds++)
#pragma unroll
      for (int kk = 0; kk < 4; kk++)
        vf[ds][kk] = *(const bf16x8*)(vb + fo[ds][kk]);

    // PV0
    __builtin_amdgcn_s_setprio(1);
#pragma unroll
    for (int ds = 0; ds < 2; ds++) {
      f32x16 a = oacc[0][ds];
      a = __builtin_amdgcn_mfma_f32_32x32x16_bf16(vf[ds][0], F[0], a, 0, 0, 0);
      a = __builtin_amdgcn_mfma_f32_32x32x16_bf16(vf[ds][1], F[1], a, 0, 0, 0);
      a = __builtin_amdgcn_mfma_f32_32x32x16_bf16(vf[ds][2], F[2], a, 0, 0, 0);
      a = __builtin_amdgcn_mfma_f32_32x32x16_bf16(vf[ds][3], F[3], a, 0, 0, 0);
      oacc[0][ds] = a;
    }
    __builtin_amdgcn_s_setprio(0);

    // exp1 on VALU while PV0 drains
    bf16x8 G[4];
    expF(S1, G, rs[1]);

    // PV1
    __builtin_amdgcn_s_setprio(1);
#pragma unroll
    for (int ds = 0; ds < 2; ds++) {
      f32x16 a = oacc[1][ds];
      a = __builtin_amdgcn_mfma_f32_32x32x16_bf16(vf[ds][0], G[0], a, 0, 0, 0);
      a = __builtin_amdgcn_mfma_f32_32x32x16_bf16(vf[ds][1], G[1], a, 0, 0, 0);
      a = __builtin_amdgcn_mfma_f32_32x32x16_bf16(vf[ds][2], G[2], a, 0, 0, 0);
      a = __builtin_amdgcn_mfma_f32_32x32x16_bf16(vf[ds][3], G[3], a, 0, 0, 0);
      oacc[1][ds] = a;
    }
    __builtin_amdgcn_s_setprio(0);
  }

  // row-sum: lane pair (q, q+32) holds complementary halves
  const int b = bh >> 4, h = bh & 15;
#pragma unroll
  for (int qb = 0; qb < 2; qb++) {
    float rt = rs[qb] + __shfl_xor(rs[qb], 32, 64);
    float inv = 1.0f / rt;
    const int trow = q0 + qb * 128 + w * 32 + l31;
#pragma unroll
    for (int ds = 0; ds < 2; ds++)
#pragma unroll
      for (int g = 0; g < 4; g++) {
        int d = ds * 32 + g * 8 + hi * 4;  // crow: 4 consecutive d per reg-quad
        u32x2 pkv = { cvtpk(oacc[qb][ds][g * 4 + 0] * inv, oacc[qb][ds][g * 4 + 1] * inv),
                      cvtpk(oacc[qb][ds][g * 4 + 2] * inv, oacc[qb][ds][g * 4 + 3] * inv) };
        *(u32x2*)(O + ((size_t)b * 2048 + trow) * 1024 + h * 64 + d) = pkv;
      }
  }
}

// ---------------------------------------------------------------------------
extern "C" void kernel_launch(void* const* d_in, const int* in_sizes, int n_in,
                              void* d_out, int out_size, void* d_ws, size_t ws_size,
                              hipStream_t stream) {
  const float* x    = (const float*)d_in[0];   // [4,2048,1024] fp32
  const float* Wqkv = (const float*)d_in[1];   // [1024,3072] fp32
  const float* Wo   = (const float*)d_in[2];   // [1024,1024] fp32
  float* out = (float*)d_out;                  // [4,2048,1024] fp32
  char* ws = (char*)d_ws;

  bf16* wqkvT = (bf16*)(ws);                        //  6 MB [3072][1024] permuted bf16
  bf16* woT   = (bf16*)(ws + 6291456);              //  2 MB [1024][1024] bf16
  bf16* xb    = (bf16*)(ws + 8388608);              // 16 MB [8192][1024] bf16
  bf16* Qb    = (bf16*)(ws + 25165824);             // 16 MB [bh][t][d]
  bf16* Kb    = (bf16*)(ws + 41943040);             // 16 MB [bh][t][d]
  bf16* VTb   = (bf16*)(ws + 58720256);             // 16 MB [bh][d][t] (direct from GEMM)
  bf16* AOb   = xb;   // x dead after QKV GEMM; reuse as attention output

  prep_all<<<8576, 256, 0, stream>>>(x, xb, Wqkv, wqkvT, Wo, woT);
  gemm_bt<1><<<dim3(64, 24), 256, 0, stream>>>(xb, wqkvT, nullptr, 3072, Qb, Kb, VTb);
  attn_fwd<<<dim3(64, 8), 256, 0, stream>>>(Qb, Kb, VTb, AOb);
  gemm_bt<0><<<dim3(64, 8), 256, 0, stream>>>(AOb, woT, out, 1024, nullptr, nullptr, nullptr);
}

// Round 9
// 257.702 us; speedup vs baseline: 1.0791x; 1.0791x over previous
//
#include <hip/hip_runtime.h>

typedef __bf16 bf16;
typedef __bf16 bf16x2 __attribute__((ext_vector_type(2)));
typedef __bf16 bf16x4 __attribute__((ext_vector_type(4)));
typedef __bf16 bf16x8 __attribute__((ext_vector_type(8)));
typedef float  f32x4  __attribute__((ext_vector_type(4)));
typedef float  f32x16 __attribute__((ext_vector_type(16)));
typedef unsigned int u32;
typedef unsigned int u32x2 __attribute__((ext_vector_type(2)));
typedef unsigned int u32x4 __attribute__((ext_vector_type(4)));

#define LOG2E 1.44269504088896340736f
#define EXP_SC (0.125f * LOG2E)   // folded into Q at the QKV-GEMM epilogue

#if __has_builtin(__builtin_amdgcn_exp2f)
#define EXP2F(x) __builtin_amdgcn_exp2f(x)
#else
#define EXP2F(x) __builtin_exp2f(x)
#endif

// fast f32 -> bf16 (round-half-up) packed pair via v_perm_b32
__device__ __forceinline__ u32 pk_bf16(float lo, float hi) {
  u32 a = __float_as_uint(lo) + 0x8000u;
  u32 b = __float_as_uint(hi) + 0x8000u;
  return __builtin_amdgcn_perm(b, a, 0x07060302);  // [bf16(lo) | bf16(hi)<<16]
}
#if __has_builtin(__builtin_amdgcn_cvt_pk_bf16_f32)
__device__ __forceinline__ u32 cvtpk(float lo, float hi) {
  bf16x2 t = __builtin_amdgcn_cvt_pk_bf16_f32(lo, hi);
  return __builtin_bit_cast(u32, t);
}
#else
__device__ __forceinline__ u32 cvtpk(float lo, float hi) { return pk_bf16(lo, hi); }
#endif
__device__ __forceinline__ unsigned short bf16r(float x) {
  return (unsigned short)((__float_as_uint(x) + 0x8000u) >> 16);
}

__device__ __forceinline__ f32x16 zero16() {
  f32x16 a;
#pragma unroll
  for (int i = 0; i < 16; i++) a[i] = 0.f;
  return a;
}

// async global->LDS, 16B per lane. LDS dest = wave-uniform base + lane*16.
__device__ __forceinline__ void async_ld16(void* lds, const void* g) {
  __builtin_amdgcn_global_load_lds(
      (const __attribute__((address_space(1))) void*)(g),
      (__attribute__((address_space(3))) void*)(lds),
      16, 0, 0);
}

// ---------------------------------------------------------------------------
// Fused prep: one launch, three block ranges (phases overlap across CUs).
//   [0, 8192)      : x fp32 -> xb bf16 (4 elems/thread)
//   [8192, 8448)   : WT_perm[n'][k] = bf16(W_qkv[k][orig_n(n')]),
//                    n' = wch*1024+h*64+dl; true d = (dl&15)*4 + (dl>>4)
//   [8448, 8576)   : WoT[n'][k] = bf16(W_o[k][orig(n')]), same within-64
//                    permutation -> MODE 0 epilogue gets consecutive cols
// ---------------------------------------------------------------------------
__global__ void prep_all(const float* __restrict__ x,    bf16* __restrict__ xb,
                         const float* __restrict__ Wqkv, bf16* __restrict__ wqkvT,
                         const float* __restrict__ Wo,   bf16* __restrict__ woT) {
  __shared__ float s[12288];                // 48 KB
  const int bid = blockIdx.x;
  const int tid = threadIdx.x;
  if (bid < 8192) {
    int i = bid * 256 + tid;
    float4 v = ((const float4*)x)[i];
    u32x2 o = { pk_bf16(v.x, v.y), pk_bf16(v.z, v.w) };
    *(u32x2*)(xb + (size_t)i * 4) = o;
  } else if (bid < 8448) {
    const int k0 = (bid - 8192) * 4;
    for (int i = tid; i < 3072; i += 256) {       // 4 rows * 768 float4
      int r = i / 768, c = (i - r * 768) * 4;
      *(float4*)(s + r * 3072 + c) = *(const float4*)(Wqkv + (size_t)(k0 + r) * 3072 + c);
    }
    __syncthreads();
    for (int n = tid; n < 3072; n += 256) {
      int dl = n & 63, h = (n >> 6) & 15, wch = n >> 10;
      int d = ((dl & 15) << 2) | (dl >> 4);       // column->d permutation
      int on = d * 48 + wch * 16 + h;
      u32x2 v = { pk_bf16(s[0 * 3072 + on], s[1 * 3072 + on]),
                  pk_bf16(s[2 * 3072 + on], s[3 * 3072 + on]) };
      *(u32x2*)(wqkvT + (size_t)n * 1024 + k0) = v;
    }
  } else {
    const int k0 = (bid - 8448) * 8;
    for (int i = tid; i < 2048; i += 256) {       // 8 rows * 256 float4
      int r = i >> 8, c = (i & 255) * 4;
      *(float4*)(s + r * 1024 + c) = *(const float4*)(Wo + (size_t)(k0 + r) * 1024 + c);
    }
    __syncthreads();
    for (int n = tid; n < 1024; n += 256) {
      int g = n >> 6, dl = n & 63;
      int on = (g << 6) | ((dl & 15) << 2) | (dl >> 4);   // within-64 permutation
      u32x4 v = { pk_bf16(s[0 * 1024 + on], s[1 * 1024 + on]),
                  pk_bf16(s[2 * 1024 + on], s[3 * 1024 + on]),
                  pk_bf16(s[4 * 1024 + on], s[5 * 1024 + on]),
                  pk_bf16(s[6 * 1024 + on], s[7 * 1024 + on]) };
      *(u32x4*)(woT + (size_t)n * 1024 + k0) = v;
    }
  }
}

// ---------------------------------------------------------------------------
// GEMM: C = A[M][1024] * BT[N][1024]^T, 128x128 tile, BK=64, 4 waves.
// Single-buffer, 2 barriers per K-step, (256,2) (best measured; R8 showed
// cap-128 spills). 1D grid + XCD-CHUNKED SWIZZLE (T1): hw round-robins
// blockIdx%8 across XCDs, so decode m = (bid&7)*8 + (bid>>3)&7, n = bid>>6:
// each XCD owns a contiguous 8-m-block stripe (A chunk = 2 MB, L2-resident)
// and streams each B-panel once. Requires grid % 8 == 0 (1536 / 512: ok).
// MODE 0: packed f32x4 C stores -- woT's within-64 column permutation makes
// each lane's 4 ns-fragments consecutive true columns.
// MODE 1: packed bf16 stores; Q/K u32x2 at [bh][t][d0=l15*4]; V packs along
// r (4 consecutive t) -> u32x2 at VT[bh][d][t]. Q pre-scaled by EXP_SC.
// ---------------------------------------------------------------------------
template <int MODE>
__launch_bounds__(256, 2)
__global__ void gemm_bt(const bf16* __restrict__ A, const bf16* __restrict__ BT,
                        float* __restrict__ C, int N,
                        bf16* __restrict__ Qb, bf16* __restrict__ Kb, bf16* __restrict__ Vb) {
  constexpr int K = 1024;
  __shared__ bf16 sA[128 * 64];             // 16 KB
  __shared__ bf16 sB[128 * 64];             // 16 KB
  const int bid = blockIdx.x;
  const int m0 = ((((bid & 7) << 3) | ((bid >> 3) & 7))) * 128;  // XCD-chunked
  const int n0 = (bid >> 6) * 128;
  const int tid = threadIdx.x;
  const int lane = tid & 63;
  const int w = tid >> 6;
  const int wm = (w >> 1) * 64, wn = (w & 1) * 64;
  const int l15 = lane & 15, quad = lane >> 4;

  f32x4 acc[4][4];
  for (int i = 0; i < 4; i++)
    for (int j = 0; j < 4; j++) acc[i][j] = f32x4{0.f, 0.f, 0.f, 0.f};

  const int rT = tid >> 3;
  const int jT = (tid & 7) ^ (rT & 7);
  const bf16* gA = A  + (size_t)(m0 + rT) * K + jT * 8;
  const bf16* gB = BT + (size_t)(n0 + rT) * K + jT * 8;

  for (int k0 = 0; k0 < K; k0 += 64) {
    __syncthreads();
    for (int i = 0; i < 4; i++) {
      async_ld16((void*)(sA + (i * 256 + w * 64) * 8), gA + (size_t)i * 32 * K);
      async_ld16((void*)(sB + (i * 256 + w * 64) * 8), gB + (size_t)i * 32 * K);
    }
    gA += 64; gB += 64;
    __syncthreads();

    for (int kk = 0; kk < 2; kk++) {
      bf16x8 af[4], bfr[4];
      for (int ms = 0; ms < 4; ms++) {
        int r = wm + ms * 16 + l15;
        af[ms] = *(const bf16x8*)(sA + r * 64 + (((kk * 4 + quad) ^ (r & 7)) * 8));
      }
      for (int ns = 0; ns < 4; ns++) {
        int r = wn + ns * 16 + l15;
        bfr[ns] = *(const bf16x8*)(sB + r * 64 + (((kk * 4 + quad) ^ (r & 7)) * 8));
      }
      for (int ms = 0; ms < 4; ms++)
        for (int ns = 0; ns < 4; ns++)
          acc[ms][ns] = __builtin_amdgcn_mfma_f32_16x16x32_bf16(af[ms], bfr[ns], acc[ms][ns], 0, 0, 0);
    }
  }

  if (MODE == 0) {
    // packed f32x4: cols n0+wn + l15*4 + {0..3} (true cols via woT perm)
    for (int ms = 0; ms < 4; ms++)
      for (int r = 0; r < 4; r++) {
        int row = m0 + wm + ms * 16 + quad * 4 + r;
        f32x4 v = { acc[ms][0][r], acc[ms][1][r], acc[ms][2][r], acc[ms][3][r] };
        *(f32x4*)(C + (size_t)row * N + n0 + wn + l15 * 4) = v;
      }
  } else {
    const int col0 = n0 + wn;                 // 64-aligned: one head per wave
    const int wch = col0 >> 10;               // uniform per block
    const int h = (col0 >> 6) & 15;           // uniform per wave
    if (wch != 2) {
      bf16* dst = (wch == 0) ? Qb : Kb;
      const float sc = (wch == 0) ? EXP_SC : 1.0f;
      for (int ms = 0; ms < 4; ms++)
        for (int r = 0; r < 4; r++) {
          int row = m0 + wm + ms * 16 + quad * 4 + r;
          int b = row >> 11, t = row & 2047;
          u32x2 v = { cvtpk(acc[ms][0][r] * sc, acc[ms][1][r] * sc),
                      cvtpk(acc[ms][2][r] * sc, acc[ms][3][r] * sc) };
          *(u32x2*)((unsigned short*)dst +
                    (((size_t)(b * 16 + h)) * 2048 + t) * 64 + l15 * 4) = v;
        }
    } else {
      for (int ms = 0; ms < 4; ms++)
        for (int ns = 0; ns < 4; ns++) {
          int row = m0 + wm + ms * 16 + quad * 4;   // rows row..row+3 = consecutive t
          int b = row >> 11, t = row & 2047;
          int d = l15 * 4 + ns;                      // permuted column -> true d
          u32x2 v = { cvtpk(acc[ms][ns][0], acc[ms][ns][1]),
                      cvtpk(acc[ms][ns][2], acc[ms][ns][3]) };
          *(u32x2*)((unsigned short*)Vb +
                    (((size_t)(b * 16 + h)) * 64 + d) * 2048 + t) = v;
        }
    }
  }
}

// ---------------------------------------------------------------------------
// Flash attention, swapped-operand 32x32 MFMA, P in registers, 2 q-blocks
// per wave, ONE barrier per tile (R7, best measured: 87.0 us; ~790 TF =
// this schedule family's ceiling per R1/R4/R7 A/B). UNCHANGED.
// ---------------------------------------------------------------------------
__launch_bounds__(256, 2)
__global__ void attn_fwd(const bf16* __restrict__ Q, const bf16* __restrict__ K,
                         const bf16* __restrict__ VT, bf16* __restrict__ O) {
  __shared__ bf16 sK[2][64 * 64];           // 16 KB  [key][d]
  __shared__ bf16 sV[2][64 * 64];           // 16 KB  [d][key]
  const int bh = blockIdx.x;
  const int q0 = blockIdx.y * 256;
  const int tid = threadIdx.x;
  const int lane = tid & 63, w = tid >> 6;
  const int l31 = lane & 31, hi = lane >> 5;

  // Q B-fragments for both q-blocks (col = q = l31, k = kq*16 + hi*8 + j)
  bf16x8 qf[2][4];
#pragma unroll
  for (int qb = 0; qb < 2; qb++) {
    const bf16* qp = Q + ((size_t)bh * 2048 + q0 + qb * 128 + w * 32 + l31) * 64 + hi * 8;
#pragma unroll
    for (int kq = 0; kq < 4; kq++) qf[qb][kq] = *(const bf16x8*)(qp + kq * 16);
  }

  f32x16 oacc[2][2];                        // [qb][ds]
  oacc[0][0] = zero16(); oacc[0][1] = zero16();
  oacc[1][0] = zero16(); oacc[1][1] = zero16();
  float rs[2] = {0.f, 0.f};

  // staging geometry: 512 16B chunks per 8KB tile.
  const int cA = w * 128 + lane;
  const int rA = cA >> 3, jA = (cA & 7) ^ (rA & 7);
  const bf16* gK = K  + ((size_t)bh * 2048 + rA) * 64 + jA * 8;   // +512: row+8
  const bf16* gV = VT + ((size_t)bh * 64 + rA) * 2048 + jA * 8;   // +16384: row+8

  // fragment offsets: row = sub*32 + l31, chunk = st*2 + hi,
  // addr = r*64 + ((chunk ^ (r&7)) * 8). Serves K (sub=ks) and V (sub=ds).
  int fo[2][4];
#pragma unroll
  for (int sub = 0; sub < 2; sub++)
#pragma unroll
    for (int st = 0; st < 4; st++) {
      int r = sub * 32 + l31;
      fo[sub][st] = r * 64 + (((st * 2 + hi) ^ (r & 7)) * 8);
    }

  auto stage = [&](bf16* kb, bf16* vb) {
    async_ld16((void*)(kb + w * 1024),        gK);
    async_ld16((void*)(kb + w * 1024 + 512),  gK + 512);
    async_ld16((void*)(vb + w * 1024),        gV);
    async_ld16((void*)(vb + w * 1024 + 512),  gV + 16384);
    gK += 4096; gV += 64;
  };

  auto expF = [&](f32x16 (&S)[2], bf16x8 (&F)[4], float& rsv) {
#pragma unroll
    for (int ks = 0; ks < 2; ks++) {
      float p[16];
#pragma unroll
      for (int r = 0; r < 16; r++) p[r] = EXP2F(S[ks][r]);
      rsv += (((p[0] + p[1]) + (p[2] + p[3])) + ((p[4] + p[5]) + (p[6] + p[7])))
           + (((p[8] + p[9]) + (p[10] + p[11])) + ((p[12] + p[13]) + (p[14] + p[15])));
      u32 c0 = cvtpk(p[0],  p[1]),  c1 = cvtpk(p[2],  p[3]);
      u32 c2 = cvtpk(p[4],  p[5]),  c3 = cvtpk(p[6],  p[7]);
      u32 c4 = cvtpk(p[8],  p[9]),  c5 = cvtpk(p[10], p[11]);
      u32 c6 = cvtpk(p[12], p[13]), c7 = cvtpk(p[14], p[15]);
      asm("v_permlane32_swap_b32 %0, %1" : "+v"(c0), "+v"(c2));
      asm("v_permlane32_swap_b32 %0, %1" : "+v"(c1), "+v"(c3));
      asm("v_permlane32_swap_b32 %0, %1" : "+v"(c4), "+v"(c6));
      asm("v_permlane32_swap_b32 %0, %1" : "+v"(c5), "+v"(c7));
      u32x4 f0 = { c0, c1, c2, c3 };
      u32x4 f1 = { c4, c5, c6, c7 };
      F[ks * 2 + 0] = __builtin_bit_cast(bf16x8, f0);
      F[ks * 2 + 1] = __builtin_bit_cast(bf16x8, f1);
    }
  };

  // prologue: stage tile 0 -> sK[0], sV[0]
  stage(sK[0], sV[0]);

  for (int t = 0; t < 32; ++t) {
    __syncthreads();                        // tile t landed; iter t-1 reads done
    const bf16* kb = sK[t & 1];
    const bf16* vb = sV[t & 1];
    // issue kf ds_reads first (LDS pipe starts), then vmem stage issue
    bf16x8 kf[2][4];
#pragma unroll
    for (int ks = 0; ks < 2; ks++)
#pragma unroll
      for (int kq = 0; kq < 4; kq++)
        kf[ks][kq] = *(const bf16x8*)(kb + fo[ks][kq]);
    if (t < 31) stage(sK[(t + 1) & 1], sV[(t + 1) & 1]);

    // QK for both q-blocks (16 MFMA, 4 independent 4-chains)
    f32x16 S0[2], S1[2];
    __builtin_amdgcn_s_setprio(1);
#pragma unroll
    for (int ks = 0; ks < 2; ks++) {
      f32x16 a = zero16();
      a = __builtin_amdgcn_mfma_f32_32x32x16_bf16(kf[ks][0], qf[0][0], a, 0, 0, 0);
      a = __builtin_amdgcn_mfma_f32_32x32x16_bf16(kf[ks][1], qf[0][1], a, 0, 0, 0);
      a = __builtin_amdgcn_mfma_f32_32x32x16_bf16(kf[ks][2], qf[0][2], a, 0, 0, 0);
      a = __builtin_amdgcn_mfma_f32_32x32x16_bf16(kf[ks][3], qf[0][3], a, 0, 0, 0);
      S0[ks] = a;
    }
#pragma unroll
    for (int ks = 0; ks < 2; ks++) {
      f32x16 a = zero16();
      a = __builtin_amdgcn_mfma_f32_32x32x16_bf16(kf[ks][0], qf[1][0], a, 0, 0, 0);
      a = __builtin_amdgcn_mfma_f32_32x32x16_bf16(kf[ks][1], qf[1][1], a, 0, 0, 0);
      a = __builtin_amdgcn_mfma_f32_32x32x16_bf16(kf[ks][2], qf[1][2], a, 0, 0, 0);
      a = __builtin_amdgcn_mfma_f32_32x32x16_bf16(kf[ks][3], qf[1][3], a, 0, 0, 0);
      S1[ks] = a;
    }
    __builtin_amdgcn_s_setprio(0);

    // exp0 on VALU while QK1 drains the MFMA pipe
    bf16x8 F[4];
    expF(S0, F, rs[0]);

    bf16x8 vf[2][4];
#pragma unroll
    for (int ds = 0; ds < 2; ds++)
#pragma unroll
      for (int kk = 0; kk < 4; kk++)
        vf[ds][kk] = *(const bf16x8*)(vb + fo[ds][kk]);

    // PV0
    __builtin_amdgcn_s_setprio(1);
#pragma unroll
    for (int ds = 0; ds < 2; ds++) {
      f32x16 a = oacc[0][ds];
      a = __builtin_amdgcn_mfma_f32_32x32x16_bf16(vf[ds][0], F[0], a, 0, 0, 0);
      a = __builtin_amdgcn_mfma_f32_32x32x16_bf16(vf[ds][1], F[1], a, 0, 0, 0);
      a = __builtin_amdgcn_mfma_f32_32x32x16_bf16(vf[ds][2], F[2], a, 0, 0, 0);
      a = __builtin_amdgcn_mfma_f32_32x32x16_bf16(vf[ds][3], F[3], a, 0, 0, 0);
      oacc[0][ds] = a;
    }
    __builtin_amdgcn_s_setprio(0);

    // exp1 on VALU while PV0 drains
    bf16x8 G[4];
    expF(S1, G, rs[1]);

    // PV1
    __builtin_amdgcn_s_setprio(1);
#pragma unroll
    for (int ds = 0; ds < 2; ds++) {
      f32x16 a = oacc[1][ds];
      a = __builtin_amdgcn_mfma_f32_32x32x16_bf16(vf[ds][0], G[0], a, 0, 0, 0);
      a = __builtin_amdgcn_mfma_f32_32x32x16_bf16(vf[ds][1], G[1], a, 0, 0, 0);
      a = __builtin_amdgcn_mfma_f32_32x32x16_bf16(vf[ds][2], G[2], a, 0, 0, 0);
      a = __builtin_amdgcn_mfma_f32_32x32x16_bf16(vf[ds][3], G[3], a, 0, 0, 0);
      oacc[1][ds] = a;
    }
    __builtin_amdgcn_s_setprio(0);
  }

  // row-sum: lane pair (q, q+32) holds complementary halves
  const int b = bh >> 4, h = bh & 15;
#pragma unroll
  for (int qb = 0; qb < 2; qb++) {
    float rt = rs[qb] + __shfl_xor(rs[qb], 32, 64);
    float inv = 1.0f / rt;
    const int trow = q0 + qb * 128 + w * 32 + l31;
#pragma unroll
    for (int ds = 0; ds < 2; ds++)
#pragma unroll
      for (int g = 0; g < 4; g++) {
        int d = ds * 32 + g * 8 + hi * 4;  // crow: 4 consecutive d per reg-quad
        u32x2 pkv = { cvtpk(oacc[qb][ds][g * 4 + 0] * inv, oacc[qb][ds][g * 4 + 1] * inv),
                      cvtpk(oacc[qb][ds][g * 4 + 2] * inv, oacc[qb][ds][g * 4 + 3] * inv) };
        *(u32x2*)(O + ((size_t)b * 2048 + trow) * 1024 + h * 64 + d) = pkv;
      }
  }
}

// ---------------------------------------------------------------------------
extern "C" void kernel_launch(void* const* d_in, const int* in_sizes, int n_in,
                              void* d_out, int out_size, void* d_ws, size_t ws_size,
                              hipStream_t stream) {
  const float* x    = (const float*)d_in[0];   // [4,2048,1024] fp32
  const float* Wqkv = (const float*)d_in[1];   // [1024,3072] fp32
  const float* Wo   = (const float*)d_in[2];   // [1024,1024] fp32
  float* out = (float*)d_out;                  // [4,2048,1024] fp32
  char* ws = (char*)d_ws;

  bf16* wqkvT = (bf16*)(ws);                        //  6 MB [3072][1024] permuted bf16
  bf16* woT   = (bf16*)(ws + 6291456);              //  2 MB [1024][1024] permuted bf16
  bf16* xb    = (bf16*)(ws + 8388608);              // 16 MB [8192][1024] bf16
  bf16* Qb    = (bf16*)(ws + 25165824);             // 16 MB [bh][t][d]
  bf16* Kb    = (bf16*)(ws + 41943040);             // 16 MB [bh][t][d]
  bf16* VTb   = (bf16*)(ws + 58720256);             // 16 MB [bh][d][t] (direct from GEMM)
  bf16* AOb   = xb;   // x dead after QKV GEMM; reuse as attention output

  prep_all<<<8576, 256, 0, stream>>>(x, xb, Wqkv, wqkvT, Wo, woT);
  gemm_bt<1><<<1536, 256, 0, stream>>>(xb, wqkvT, nullptr, 3072, Qb, Kb, VTb);
  attn_fwd<<<dim3(64, 8), 256, 0, stream>>>(Qb, Kb, VTb, AOb);
  gemm_bt<0><<<512, 256, 0, stream>>>(AOb, woT, out, 1024, nullptr, nullptr, nullptr);
}